// Round 15
// baseline (1050.493 us; speedup 1.0000x reference)
//
#include <hip/hip_runtime.h>

#define SEQ   1024
#define BATCH 512
#define HID   128

typedef __attribute__((ext_vector_type(8))) short          short8v;
typedef __attribute__((ext_vector_type(4))) float          float4v;
typedef __attribute__((ext_vector_type(8))) unsigned short ushort8v;

__device__ __forceinline__ unsigned short f2bf(float f) {
    union { float f; unsigned u; } v; v.f = f;
    return (unsigned short)((v.u + 0x7fffu + ((v.u >> 16) & 1u)) >> 16);
}
__device__ __forceinline__ float bf2f(unsigned short u) {
    union { unsigned u; float f; } v; v.u = ((unsigned)u) << 16;
    return v.f;
}
__device__ __forceinline__ unsigned packbf(float a, float b) {
    return (unsigned)f2bf(a) | ((unsigned)f2bf(b) << 16);
}
__device__ __forceinline__ float fast_cos(float x) {
    return __builtin_amdgcn_cosf(x * 0.15915494309189535f);   // v_cos takes revolutions
}
__device__ __forceinline__ float fast_sigmoid(float x) {
    return __builtin_amdgcn_rcpf(1.0f + __builtin_amdgcn_exp2f(-1.4426950408889634f * x));
}
__device__ __forceinline__ float fast_tanh(float x) {
    return 1.0f - 2.0f * __builtin_amdgcn_rcpf(1.0f + __builtin_amdgcn_exp2f(2.8853900817779268f * x));
}
template<int CTRL, int RM>
__device__ __forceinline__ float dpp1(float v) {
    union { float f; int i; } s, o, r;
    s.f = v; o.f = 1.0f;
    r.i = __builtin_amdgcn_update_dpp(o.i, s.i, CTRL, RM, 0xf, false);
    return r.f;
}
#define BAR() do { asm volatile("s_waitcnt lgkmcnt(0)" ::: "memory");  \
                   __builtin_amdgcn_s_barrier();                       \
                   __builtin_amdgcn_sched_barrier(0); } while (0)

// LDS swizzles (R13-verified): bijective in col; hot accesses <=2-way.
__device__ __forceinline__ int zswz(int slot, int g, int c) {
    return slot * 512 + g * 128 + (c ^ ((c >> 5) << 4) ^ ((slot & 2) << 3));
}
__device__ __forceinline__ int gswz(int row, int g, int c) {
    return row * 512 + g * 128 + (c ^ ((c >> 5) << 4));
}

// ---------------------------------------------------------------------------
// ONE persistent kernel. 256 WGs x 512 thr (8 waves, 2/SIMD), 2 rows/WG, 1 WG/CU.
// Wave w = (gate g=w>>1, col-half hb=w&1): owns 64 gate-cols = 4 MFMA tiles.
// Phase A (all 8 waves):
//   16-MFMA h-GEMM (2 rows replicated in M, W_h frags in regs) + one 4-MFMA
//   x-tile of the NEXT 8-step window (each wave covers its 4 tiles on 4 of 8
//   steps) + z-add from bf16 ring + activation of ONE col x 2 rows per lane.
//   Waves 0/1 (f-gate): lane order == col order -> 4-DPP 16-lane scan +
//   3-shfl stitch per row = inclusive cumprod of the half; wave0 lane63
//   publishes half-totals to scanT. S1.
// Phase B: waves 0-3 cell update (1 (row,col)/lane; cols>=64 multiply by
//   scanT[row]); waves 4-7 publish staged x (w==4). S2.
// x-window staging/macros verbatim from R13/R14 (refcheck'd).
// ---------------------------------------------------------------------------
__global__ __launch_bounds__(512, 1) void qlstm_fused(
    const float* __restrict__ X,
    const float* __restrict__ Wf, const float* __restrict__ bfp,
    const float* __restrict__ Wi, const float* __restrict__ bip,
    const float* __restrict__ Wg, const float* __restrict__ bgp,
    const float* __restrict__ Wo, const float* __restrict__ bop,
    float* __restrict__ out)
{
    __shared__ unsigned zr_lds[16 * 4 * 128];                 // 32 KB bf16 row-pair z ring
    __shared__ float    ga_lds[2 * 4 * 128];                  // 4 KB activated gates
    __shared__ alignas(8)  unsigned short h_bf[2][HID];       // 512 B
    __shared__ alignas(16) unsigned short x_win[2][16][HID];  // 8 KB x window dbuf
    __shared__ float scanT[2];                                // f half-totals per row

    const int tid = threadIdx.x, lane = tid & 63, wid = tid >> 6;
    const int l15 = lane & 15, kg = lane >> 4;
    const int b0 = blockIdx.x * 2;
    const int g  = wid >> 1;                 // gate 0..3
    const int hb = wid & 1;                  // col-half
    const int cb = hb * 64;                  // col base within gate
    const float* Wsel = (g == 0) ? Wf : (g == 1) ? Wi : (g == 2) ? Wg : Wo;
    const float* bsel = (g == 0) ? bfp : (g == 1) ? bip : (g == 2) ? bgp : bop;

    // weight frags for this wave's 4 tiles: W_h (k 128..255) and W_x (k 0..127)
    short8v bwh[4][4], bwx[4][4];
    #pragma unroll
    for (int n = 0; n < 4; ++n) {
        const int col = cb + n * 16 + l15;
        #pragma unroll
        for (int ks = 0; ks < 4; ++ks) {
            short8v wh, wx;
            #pragma unroll
            for (int j = 0; j < 8; ++j) {
                const int k = ks * 32 + kg * 8 + j;
                wx[j] = (short)f2bf(Wsel[(size_t)k * HID + col]);
                wh[j] = (short)f2bf(Wsel[(size_t)(128 + k) * HID + col]);
            }
            bwx[n][ks] = wx;
            bwh[n][ks] = wh;
        }
    }
    float biasr[4];
    #pragma unroll
    for (int n = 0; n < 4; ++n) biasr[n] = bsel[cb + n * 16 + l15];

    if (tid < 128) ((unsigned*)h_bf)[tid] = 0u;   // h0 = 0

    // Phase-B cell geometry (waves 0-3): wave -> (row, col-half)
    const int crow = wid >> 1;                    // 0,0,1,1
    const int ccol = (wid & 1) * 64 + lane;
    float c_reg = 0.f, h_last = 0.f;
    const int c_act = cb + lane;                  // Phase-A activation col (lane order!)

    // x_win staging geometry (waves 4-7; pt 0..255): row m = 2*step_local+row
    const int pt  = tid & 255;
    const int sm  = (pt >> 4) & 15;
    const int sbl = pt & 15;
    const size_t xrow_off = ((size_t)(b0 + (sm & 1))) * HID + sbl * 8;
    const int xw_off = (sbl * 16) ^ ((sm & 7) << 4);
    const int xsw = (l15 & 7) << 4;

#define STAGE_XWIN(buf, s0) do {                                                   \
    const float* xp_ = X + ((size_t)((s0) + (sm >> 1)) * BATCH) * HID + xrow_off;  \
    float4v a_ = *(const float4v*)xp_;                                             \
    float4v b_ = *(const float4v*)(xp_ + 4);                                       \
    ushort8v o_;                                                                   \
    o_[0]=f2bf(a_[0]); o_[1]=f2bf(a_[1]); o_[2]=f2bf(a_[2]); o_[3]=f2bf(a_[3]);    \
    o_[4]=f2bf(b_[0]); o_[5]=f2bf(b_[1]); o_[6]=f2bf(b_[2]); o_[7]=f2bf(b_[3]);    \
    *(ushort8v*)((char*)&x_win[buf][sm][0] + xw_off) = o_;                         \
} while (0)

#define LOAD_AX(buf) do {                                                          \
    const char* xb_ = (const char*)&x_win[buf][0][0] + l15 * 256;                  \
    ax[0] = *(const short8v*)(xb_ + ((      kg * 16) ^ xsw));                      \
    ax[1] = *(const short8v*)(xb_ + (( 64 + kg * 16) ^ xsw));                      \
    ax[2] = *(const short8v*)(xb_ + ((128 + kg * 16) ^ xsw));                      \
    ax[3] = *(const short8v*)(xb_ + ((192 + kg * 16) ^ xsw));                      \
} while (0)

// 4-MFMA x-tile (local tile i); lane(kg,l15) reg j -> step kg*2+(j>>1),
// row j&1, col cb+i*16+l15. (R13-verified mapping)
#define XTILE(i) do {                                                              \
    float4v xa_;                                                                   \
    xa_[0] = biasr[i]; xa_[1] = biasr[i]; xa_[2] = biasr[i]; xa_[3] = biasr[i];    \
    xa_ = __builtin_amdgcn_mfma_f32_16x16x32_bf16(ax[0], bwx[i][0], xa_, 0, 0, 0); \
    xa_ = __builtin_amdgcn_mfma_f32_16x16x32_bf16(ax[1], bwx[i][1], xa_, 0, 0, 0); \
    xa_ = __builtin_amdgcn_mfma_f32_16x16x32_bf16(ax[2], bwx[i][2], xa_, 0, 0, 0); \
    xa_ = __builtin_amdgcn_mfma_f32_16x16x32_bf16(ax[3], bwx[i][3], xa_, 0, 0, 0); \
    const int se_ = (bnext + kg * 2) & 15;                                         \
    const int cs_ = cb + (i) * 16 + l15;                                           \
    zr_lds[zswz(se_,           g, cs_)] = packbf(xa_[0], xa_[1]);                  \
    zr_lds[zswz((se_ + 1) & 15, g, cs_)] = packbf(xa_[2], xa_[3]);                 \
} while (0)

    short8v ax[4];                 // current-window x A-frags
    float4v xg0 = {}, xg1 = {};    // staged x (issued w==0, published w==4)

    // ---- prologue: stage x_win[0]<-x[0..7], x_win[1]<-x[8..15]; z slots 0..7
    if (wid >= 4) { STAGE_XWIN(0, 0); STAGE_XWIN(1, 8); }
    BAR();
    {
        LOAD_AX(0);
        float4v pacc[4];
        #pragma unroll
        for (int n = 0; n < 4; ++n)
            #pragma unroll
            for (int j = 0; j < 4; ++j) pacc[n][j] = biasr[n];
        #pragma unroll
        for (int ks = 0; ks < 4; ++ks)
            #pragma unroll
            for (int n = 0; n < 4; ++n)
                pacc[n] = __builtin_amdgcn_mfma_f32_16x16x32_bf16(ax[ks], bwx[n][ks], pacc[n], 0, 0, 0);
        #pragma unroll
        for (int n = 0; n < 4; ++n) {
            const int se_ = kg * 2;
            const int cs_ = cb + n * 16 + l15;
            zr_lds[zswz(se_,     g, cs_)] = packbf(pacc[n][0], pacc[n][1]);
            zr_lds[zswz(se_ + 1, g, cs_)] = packbf(pacc[n][2], pacc[n][3]);
        }
    }
    BAR();

    #pragma unroll 1
    for (int t = 0; t < SEQ; ++t) {
        const int w = t & 7;
        const int W = t >> 3;
        const int bnext = (t & ~7) + 8;

        // ---------------- Phase A (all 8 waves) ----------------
        const unsigned zp = zr_lds[zswz(t & 15, g, c_act)];   // early z read
        short8v ah[4];
        #pragma unroll
        for (int ks = 0; ks < 4; ++ks)
            ah[ks] = *(const short8v*)&h_bf[l15 & 1][ks * 32 + kg * 8];

        if (w == 0) {
            if (bnext < SEQ) LOAD_AX((W + 1) & 1);
            if (wid >= 4 && bnext + 8 < SEQ) {   // issue global x loads
                const float* xp = X + ((size_t)(bnext + 8 + (sm >> 1)) * BATCH) * HID + xrow_off;
                xg0 = *(const float4v*)xp;
                xg1 = *(const float4v*)(xp + 4);
            }
        }

        // h-GEMM: 16 MFMA (4 tiles x 4 ks), rows replicated in M
        float4v acc[4];
        #pragma unroll
        for (int n = 0; n < 4; ++n)
            #pragma unroll
            for (int j = 0; j < 4; ++j) acc[n][j] = 0.f;
        __builtin_amdgcn_s_setprio(1);
        #pragma unroll
        for (int ks = 0; ks < 4; ++ks)
            #pragma unroll
            for (int n = 0; n < 4; ++n)
                acc[n] = __builtin_amdgcn_mfma_f32_16x16x32_bf16(ah[ks], bwh[n][ks], acc[n], 0, 0, 0);
        __builtin_amdgcn_s_setprio(0);

        // one x-tile of next window (this wave's turn on 4 of 8 steps)
        if (bnext < SEQ && (w & 1) == hb) {
            switch (w >> 1) {
                case 0: XTILE(0); break;
                case 1: XTILE(1); break;
                case 2: XTILE(2); break;
                default: XTILE(3); break;
            }
        }

        // extract this lane's col (tile kg, col c_act), rows = reg 0/1
        float s0 = ((kg == 0) ? acc[0][0] : (kg == 1) ? acc[1][0]
                  : (kg == 2) ? acc[2][0] : acc[3][0]) + bf2f((unsigned short)(zp & 0xffffu));
        float s1 = ((kg == 0) ? acc[0][1] : (kg == 1) ? acc[1][1]
                  : (kg == 2) ? acc[2][1] : acc[3][1]) + bf2f((unsigned short)(zp >> 16));

        float v0, v1;
        if (g == 0) {
            // inclusive cumprod of cos over this half's 64 cols (lane order == col order)
            float S0 = fast_cos(s0), S1 = fast_cos(s1);
            S0 *= dpp1<0x111, 0xf>(S0);  S1 *= dpp1<0x111, 0xf>(S1);
            S0 *= dpp1<0x112, 0xf>(S0);  S1 *= dpp1<0x112, 0xf>(S1);
            S0 *= dpp1<0x114, 0xf>(S0);  S1 *= dpp1<0x114, 0xf>(S1);
            S0 *= dpp1<0x118, 0xf>(S0);  S1 *= dpp1<0x118, 0xf>(S1);
            const float T00 = __shfl(S0, 15), T01 = __shfl(S0, 31), T02 = __shfl(S0, 47);
            const float T10 = __shfl(S1, 15), T11 = __shfl(S1, 31), T12 = __shfl(S1, 47);
            const float rp0 = (kg == 0) ? 1.f : (kg == 1) ? T00
                            : (kg == 2) ? T00 * T01 : T00 * T01 * T02;
            const float rp1 = (kg == 0) ? 1.f : (kg == 1) ? T10
                            : (kg == 2) ? T10 * T11 : T10 * T11 * T12;
            v0 = rp0 * S0;                       // raw inclusive (final f made in Phase B)
            v1 = rp1 * S1;
            if (wid == 0 && lane == 63) { scanT[0] = v0; scanT[1] = v1; }
        } else if (g == 1) {
            v0 = (fast_cos(s0) + 1.f) * .5f;
            v1 = (fast_cos(s1) + 1.f) * .5f;
        } else if (g == 2) {
            v0 = fast_tanh(s0);
            v1 = fast_tanh(s1);
        } else {
            v0 = fast_sigmoid(s0);
            v1 = fast_sigmoid(s1);
        }
        ga_lds[gswz(0, g, c_act)] = v0;
        ga_lds[gswz(1, g, c_act)] = v1;

        BAR();  // S1: gact + scanT + zring tile published

        // ---------------- Phase B ----------------
        if (wid < 4) {
            float fv = ga_lds[gswz(crow, 0, ccol)];
            if (wid & 1) fv *= scanT[crow];                  // cross-half cumprod fixup
            const float f  = (fv + 1.f) * 0.5f;
            const float iv = ga_lds[gswz(crow, 1, ccol)];
            const float gv = ga_lds[gswz(crow, 2, ccol)];
            const float ov = ga_lds[gswz(crow, 3, ccol)];
            const float cn = fmaf(f, c_reg, iv * gv);
            const float hn = ov * fast_tanh(cn);
            c_reg = cn; h_last = hn;
            h_bf[crow][ccol] = f2bf(hn);
            out[((size_t)t * BATCH + b0 + crow) * HID + ccol] = hn;
        } else if (w == 4 && bnext + 8 < SEQ) {
            // publish staged x (loaded at w==0) for window W+2
            ushort8v o_;
            o_[0]=f2bf(xg0[0]); o_[1]=f2bf(xg0[1]); o_[2]=f2bf(xg0[2]); o_[3]=f2bf(xg0[3]);
            o_[4]=f2bf(xg1[0]); o_[5]=f2bf(xg1[1]); o_[6]=f2bf(xg1[2]); o_[7]=f2bf(xg1[3]);
            *(ushort8v*)((char*)&x_win[W & 1][sm][0] + xw_off) = o_;
        }
        BAR();  // S2: h_bf (and x_win) ready
    }

    // final hx/cx tails (waves 0-3 hold their (row,col) last-step values)
    if (wid < 4) {
        const size_t base = (size_t)SEQ * BATCH * HID;
        const size_t ro = (size_t)(b0 + crow) * HID + ccol;
        out[base + ro] = h_last;
        out[base + (size_t)BATCH * HID + ro] = c_reg;
    }
#undef STAGE_XWIN
#undef LOAD_AX
#undef XTILE
}

// ---------------------------------------------------------------------------
extern "C" void kernel_launch(void* const* d_in, const int* in_sizes, int n_in,
                              void* d_out, int out_size, void* d_ws, size_t ws_size,
                              hipStream_t stream) {
    const float* X  = (const float*)d_in[0];
    const float* Wf = (const float*)d_in[1];
    const float* bf = (const float*)d_in[2];
    const float* Wi = (const float*)d_in[3];
    const float* bi = (const float*)d_in[4];
    const float* Wg = (const float*)d_in[5];
    const float* bg = (const float*)d_in[6];
    const float* Wo = (const float*)d_in[7];
    const float* bo = (const float*)d_in[8];
    float* out = (float*)d_out;
    (void)d_ws; (void)ws_size;

    qlstm_fused<<<BATCH / 2, 512, 0, stream>>>(
        X, Wf, bf, Wi, bi, Wg, bg, Wo, bo, out);
}